// Round 12
// baseline (210.272 us; speedup 1.0000x reference)
//
#include <hip/hip_runtime.h>
#include <hip/hip_bf16.h>

#define NH 12
#define HD 64
#define SEQ 1024
#define BATCH 8
#define DIM 768
#define QKVN 2304
#define ROWS 8192   // BATCH*SEQ

typedef __bf16 bf16x8 __attribute__((ext_vector_type(8)));
typedef float f32x4 __attribute__((ext_vector_type(4)));
typedef unsigned short u16x8 __attribute__((ext_vector_type(8)));
typedef unsigned short u16x4 __attribute__((ext_vector_type(4)));
typedef short s16x4 __attribute__((ext_vector_type(4)));

__device__ __forceinline__ unsigned short f2bf(float f) {
  union { float f; unsigned int u; } c; c.f = f;
  unsigned int u = c.u;
  u += 0x7fffu + ((u >> 16) & 1u);   // RNE; inputs are normal floats
  return (unsigned short)(u >> 16);
}

__device__ __forceinline__ unsigned int pk_bf16(float a, float b) {
  // packed RNE f32->bf16 pair (v_cvt_pk_bf16_f32 on gfx950)
  union { __hip_bfloat162 h; unsigned int w; } u;
  u.h = __float22bfloat162_rn(float2{a, b});
  return u.w;
}

__device__ __forceinline__ float exp2_fast(float x) {
  // raw v_exp_f32 (computes 2^x). q-scale has log2e folded in at the qkv GEMM,
  // so softmax base-2 here is mathematically exact vs base-e.
  float r;
  asm("v_exp_f32 %0, %1" : "=v"(r) : "v"(x));
  return r;
}

__device__ __forceinline__ void gload_lds16(const unsigned short* g, unsigned short* l) {
  __builtin_amdgcn_global_load_lds(
      (const __attribute__((address_space(1))) void*)g,
      (__attribute__((address_space(3))) void*)l, 16, 0, 0);
}

// ---------------- fused prep: f32->bf16 cast + both weight transposes ----------------
__device__ __forceinline__ void tr_tile(const float* __restrict__ src, unsigned short* __restrict__ dst,
                                        int R, int C, int bx, int by, float tile[32][33]) {
  int tx = threadIdx.x & 31, ty = threadIdx.x >> 5;   // 32 x 8
  int c0 = bx * 32, r0 = by * 32;
#pragma unroll
  for (int i = 0; i < 4; ++i)
    tile[ty + i * 8][tx] = src[(size_t)(r0 + ty + i * 8) * C + c0 + tx];
  __syncthreads();
#pragma unroll
  for (int i = 0; i < 4; ++i)
    dst[(size_t)(c0 + ty + i * 8) * R + r0 + tx] = f2bf(tile[tx][ty + i * 8]);
}

__global__ void prep_kernel(const float* __restrict__ x, unsigned short* __restrict__ xb,
                            const float* __restrict__ w_qkv, unsigned short* __restrict__ wqkvT,
                            const float* __restrict__ w_proj, unsigned short* __restrict__ wprojT) {
  __shared__ float tile[32][33];
  int blk = blockIdx.x;
  if (blk < 6144) {
    int i = blk * 256 + threadIdx.x;   // n4 = 8192*768/4 = 1572864 = 6144*256 exactly
    float4 v = ((const float4*)x)[i];
    unsigned int lo = pk_bf16(v.x, v.y), hi = pk_bf16(v.z, v.w);
    union { unsigned int w[2]; u16x4 o; } u; u.w[0] = lo; u.w[1] = hi;
    ((u16x4*)xb)[i] = u.o;
  } else if (blk < 6144 + 1728) {
    int t = blk - 6144;                // w_qkv: 768x2304 -> 24 x 72 tiles
    tr_tile(w_qkv, wqkvT, DIM, QKVN, t % 72, t / 72, tile);
  } else {
    int t = blk - 6144 - 1728;         // w_proj: 768x768 -> 24 x 24 tiles
    tr_tile(w_proj, wprojT, DIM, DIM, t % 24, t / 24, tile);
  }
}

// ---------------- 128x192 bf16 GEMM (qkv), dbuf, 1 barrier/K-iter ----------------
// R1 retile: 768 blocks = exactly 3/CU. R8 lesson: the implicit wave overlap at 3
// blocks/CU IS the pipeline — counted-vmcnt/triple-buffer grafts regressed (R7).
template <bool BF16_OUT, bool SCALE_Q>
__global__ __launch_bounds__(256, 3) void gemm192(
    const unsigned short* __restrict__ A, const unsigned short* __restrict__ BT,
    void* __restrict__ Cout, const float* __restrict__ bias,
    int M, int N, int K, int nbyXCD) {
  __shared__ unsigned short As[2][128 * 32];   // 8 KB / buf
  __shared__ unsigned short Bs[2][192 * 32];   // 12 KB / buf
  const int tid = threadIdx.x;
  const int wave = tid >> 6, lane = tid & 63, quad = lane >> 4, l16 = lane & 15;
  const int wm = wave >> 1, wn = wave & 1;     // 2x2 waves -> per-wave 64x96
  const int g = blockIdx.x & 7, bi = blockIdx.x >> 3;
  const int by = g * nbyXCD + (bi % nbyXCD);
  const int bx = bi / nbyXCD;
  const int bm = by * 128, bn = bx * 192;

  const int r0 = tid >> 2, kc0 = (tid & 3) * 8;
  const unsigned short* Ag = A + (size_t)(bm + r0) * K + kc0;
  const unsigned short* Bg = BT + (size_t)(bn + r0) * K + kc0;
  unsigned short* AsB = &As[0][0];
  unsigned short* BsB = &Bs[0][0];
  const int wdst = (tid & ~63) * 8;   // wave-uniform LDS chunk base (u16)

#define STAGE_G(kt, b) do {                                                   \
    int koff_ = (kt) * 32;                                                    \
    gload_lds16(Ag + koff_,                    AsB + (b) * 4096 + wdst);      \
    gload_lds16(Ag + koff_ + (size_t)64 * K,   AsB + (b) * 4096 + wdst + 2048);\
    gload_lds16(Bg + koff_,                    BsB + (b) * 6144 + wdst);      \
    gload_lds16(Bg + koff_ + (size_t)64 * K,   BsB + (b) * 6144 + wdst + 2048);\
    gload_lds16(Bg + koff_ + (size_t)128 * K,  BsB + (b) * 6144 + wdst + 4096);\
  } while (0)

  f32x4 zero4 = {0.f, 0.f, 0.f, 0.f};
  f32x4 acc[4][6];
#pragma unroll
  for (int i = 0; i < 4; ++i)
#pragma unroll
    for (int j = 0; j < 6; ++j) acc[i][j] = zero4;

  const int nkt = K >> 5;
  STAGE_G(0, 0);   // prologue: tile 0 -> buf 0
  for (int kt = 0; kt < nkt; ++kt) {
    __syncthreads();   // buf[kt&1] staged; reads of buf[(kt+1)&1] from kt-1 done
    if (kt + 1 < nkt) STAGE_G(kt + 1, (kt + 1) & 1);
    const unsigned short* Ab = AsB + (kt & 1) * 4096;
    const unsigned short* Bb = BsB + (kt & 1) * 6144;
    bf16x8 af[4], bf[6];
#pragma unroll
    for (int mt = 0; mt < 4; ++mt)
      af[mt] = *(const bf16x8*)&Ab[(wm * 64 + mt * 16 + l16) * 32 + quad * 8];
#pragma unroll
    for (int nt = 0; nt < 6; ++nt)
      bf[nt] = *(const bf16x8*)&Bb[(wn * 96 + nt * 16 + l16) * 32 + quad * 8];
#pragma unroll
    for (int mt = 0; mt < 4; ++mt)
#pragma unroll
      for (int nt = 0; nt < 6; ++nt)
        acc[mt][nt] = __builtin_amdgcn_mfma_f32_16x16x32_bf16(af[mt], bf[nt], acc[mt][nt], 0, 0, 0);
  }
#undef STAGE_G

#pragma unroll
  for (int mt = 0; mt < 4; ++mt)
#pragma unroll
    for (int nt = 0; nt < 6; ++nt) {
      int col = bn + wn * 96 + nt * 16 + l16;
      float bv = BF16_OUT ? 0.f : bias[col];
      // q-scale 0.125 with log2e folded in (attn uses base-2 exp; exact fold)
      float scl = (SCALE_Q && col < DIM) ? 0.18033688011112042f : 1.0f;
#pragma unroll
      for (int r = 0; r < 4; ++r) {
        int row = bm + wm * 64 + mt * 16 + quad * 4 + r;
        float v = acc[mt][nt][r];
        if (BF16_OUT)
          ((unsigned short*)Cout)[(size_t)row * N + col] = f2bf(v * scl);
        else
          ((float*)Cout)[(size_t)row * N + col] = v + bv;
      }
    }
}

// ---------------- 128x64 bf16 GEMM for proj, BK=64 (R6-verified config) ----------------
// Chunk-XOR swizzle both sides. LDS 48 KB -> 3 blocks/CU. (256,4) caps VGPR at 128.
__global__ __launch_bounds__(256, 4) void gemm64_proj(
    const unsigned short* __restrict__ A, const unsigned short* __restrict__ BT,
    float* __restrict__ Cout, const float* __restrict__ bias,
    int M, int N, int K, int nbyXCD) {
  __shared__ unsigned short As[2][128 * 64];   // 16 KB / buf
  __shared__ unsigned short Bs[2][64 * 64];    // 8 KB / buf
  const int tid = threadIdx.x;
  const int wave = tid >> 6, lane = tid & 63, quad = lane >> 4, l16 = lane & 15;
  const int g = blockIdx.x & 7, bi = blockIdx.x >> 3;
  const int by = g * nbyXCD + (bi % nbyXCD);
  const int bx = bi / nbyXCD;
  const int bm = by * 128, bn = bx * 64;

  const int r0 = tid >> 3;                       // 0..31 (row within a 32-row call)
  const int csw = ((tid & 7) ^ (r0 & 7)) * 8;    // XOR-swizzled source col chunk
  const unsigned short* Ag = A + (size_t)(bm + r0) * K + csw;
  const unsigned short* Bg = BT + (size_t)(bn + r0) * K + csw;
  unsigned short* AsB = &As[0][0];
  unsigned short* BsB = &Bs[0][0];
  const int wdst = (tid & ~63) * 8;   // wave-uniform; per-lane dest = tid*8 (linear)

#define STAGE_P(kt, b) do {                                                     \
    int koff_ = (kt) * 64;                                                      \
    gload_lds16(Ag + koff_,                   AsB + (b) * 8192 + wdst);         \
    gload_lds16(Ag + koff_ + (size_t)32 * K,  AsB + (b) * 8192 + wdst + 2048);  \
    gload_lds16(Ag + koff_ + (size_t)64 * K,  AsB + (b) * 8192 + wdst + 4096);  \
    gload_lds16(Ag + koff_ + (size_t)96 * K,  AsB + (b) * 8192 + wdst + 6144);  \
    gload_lds16(Bg + koff_,                   BsB + (b) * 4096 + wdst);         \
    gload_lds16(Bg + koff_ + (size_t)32 * K,  BsB + (b) * 4096 + wdst + 2048);  \
  } while (0)

  f32x4 zero4 = {0.f, 0.f, 0.f, 0.f};
  f32x4 acc[2][4];
#pragma unroll
  for (int i = 0; i < 2; ++i)
#pragma unroll
    for (int j = 0; j < 4; ++j) acc[i][j] = zero4;

  const int nkt = K >> 6;   // 12
  STAGE_P(0, 0);
  for (int kt = 0; kt < nkt; ++kt) {
    __syncthreads();
    if (kt + 1 < nkt) STAGE_P(kt + 1, (kt + 1) & 1);
    const unsigned short* Ab = AsB + (kt & 1) * 8192;
    const unsigned short* Bb = BsB + (kt & 1) * 4096;
#pragma unroll
    for (int kk = 0; kk < 2; ++kk) {
      const int pc = ((kk * 4 + quad) ^ (l16 & 7)) * 8;   // physical chunk (swizzled)
      bf16x8 af[2], bf[4];
#pragma unroll
      for (int mt = 0; mt < 2; ++mt)
        af[mt] = *(const bf16x8*)&Ab[(wave * 32 + mt * 16 + l16) * 64 + pc];
#pragma unroll
      for (int nt = 0; nt < 4; ++nt)
        bf[nt] = *(const bf16x8*)&Bb[(nt * 16 + l16) * 64 + pc];
#pragma unroll
      for (int mt = 0; mt < 2; ++mt)
#pragma unroll
        for (int nt = 0; nt < 4; ++nt)
          acc[mt][nt] = __builtin_amdgcn_mfma_f32_16x16x32_bf16(af[mt], bf[nt], acc[mt][nt], 0, 0, 0);
    }
  }
#undef STAGE_P

#pragma unroll
  for (int mt = 0; mt < 2; ++mt)
#pragma unroll
    for (int nt = 0; nt < 4; ++nt) {
      int col = bn + nt * 16 + l16;
      float bv = bias[col];
#pragma unroll
      for (int r = 0; r < 4; ++r) {
        int row = bm + wave * 32 + mt * 16 + quad * 4 + r;
        Cout[(size_t)row * N + col] = acc[mt][nt][r] + bv;
      }
    }
}

// ---------------- flash attention: Q-tile 128, KEY-SPLIT 8 waves, KV-tile 64 ----------------
// R11: attn is LDS-PIPE-THROUGHPUT-bound (model: 240 LDS-cy/wave-jt x 24 waves =
// 5760+770conf ~= 6530 vs measured 6750 cy/jt). Fix = halve per-wave LDS reads while
// KEEPING 512 threads (R2's failure was halving waves). 8 waves = 4 q-groups x 2
// key-halves: each wave does 32 queries (2 proven R2 sub-tiles) x its 32-key half.
// K-reads 8->4 b128, V-reads 16->8 b64 (each feeds 2 subtile MFMAs); MFMA/exp counts
// per wave UNCHANGED. O/lsum khalf-partial -> one end-of-kernel pair reduction via
// LDS scratch (aliases K/V buffers, barrier-separated; 34.8 KB <= 35.8 KB).
#define VS 76   // Vts row stride (u16)
__global__ __launch_bounds__(512, 6) void attn_kernel(
    const unsigned short* __restrict__ qkv, unsigned short* __restrict__ out) {
  __shared__ unsigned short lds[2 * 64 * 64 + 2 * 64 * VS];   // Ks | Vts, 35840 B
  unsigned short* Ks = lds;                    // [2][64*64], [kk][n][32] split layout
  unsigned short* Vts = lds + 2 * 64 * 64;     // [2][64*VS], V^T [d][n]

  const int tid = threadIdx.x;
  const int wave = tid >> 6, lane = tid & 63, quad = lane >> 4, l16 = lane & 15;
  const int qg = wave >> 1, kh = wave & 1;     // q-group 0..3, key-half 0..1
  // XCD-locality swizzle: all 8 q-tiles of one (b,h) share id%8 -> same XCD
  const int x = blockIdx.x;
  const int qt = (x >> 3) & 7;
  const int bh = (x & 7) + 8 * (x >> 6);
  const int b = bh / NH, h = bh % NH;
  const int qcol = h * HD, kcol = DIM + h * HD, vcol = 2 * DIM + h * HD;
  const int rowQ0 = b * SEQ + qt * 128;
  const int rowKV0 = b * SEQ;

  // staging index precompute (cooperative over the FULL 64-key tile — unchanged)
  const int kk_s = tid >> 8, rem_s = tid & 255, n_s = rem_s >> 2, kc_s = rem_s & 3;
  const unsigned short* kgp = qkv + (size_t)(rowKV0 + n_s) * QKVN + kcol + kk_s * 32 + kc_s * 8;
  unsigned short* klp = Ks + (tid & ~63) * 8;   // wave-uniform base (u16 units)
  const int vn = tid & 63, vd0 = (tid >> 6) * 8;
  const unsigned short* vgp = qkv + (size_t)(rowKV0 + vn) * QKVN + vcol + vd0;

  // ---- Q fragments straight from global: 2 sub-tiles of 16 q-rows per wave ----
  bf16x8 qf[2][2];
#pragma unroll
  for (int sub = 0; sub < 2; ++sub) {
    const unsigned short* qp = qkv + (size_t)(rowQ0 + qg * 32 + sub * 16 + l16) * QKVN + qcol + quad * 8;
    qf[sub][0] = *(const bf16x8*)qp;
    qf[sub][1] = *(const bf16x8*)(qp + 32);
  }

  // ---- prologue: stage tile 0 into buffer 0 ----
  gload_lds16(kgp, klp);
  {
    u16x8 v0 = *(const u16x8*)vgp;
    unsigned short* vb = Vts;
#pragma unroll
    for (int e = 0; e < 8; ++e)
      vb[(vd0 + e) * VS + vn] = v0[e];
  }

  f32x4 zero4 = {0.f, 0.f, 0.f, 0.f};
  f32x4 o[2][4];
#pragma unroll
  for (int sub = 0; sub < 2; ++sub)
#pragma unroll
    for (int dt = 0; dt < 4; ++dt) o[sub][dt] = zero4;
  float lsum[2] = {0.f, 0.f};

  for (int jt = 0; jt < 16; ++jt) {
    __syncthreads();   // drains K-DMA(jt) + vload(jt): both one compute phase old
    u16x8 vnext;
    if (jt < 15) {
      gload_lds16(kgp + (size_t)(jt + 1) * 64 * QKVN, klp + ((jt + 1) & 1) * 4096);
      vnext = *(const u16x8*)(vgp + (size_t)(jt + 1) * 64 * QKVN);
    }

    const unsigned short* Kb = Ks + (jt & 1) * 4096;
    const unsigned short* Vb = Vts + (jt & 1) * (64 * VS);

    // ---- S^T = K Q^T on this wave's 32-key half; K-frag read once, used twice ----
    f32x4 s[2][2];
#pragma unroll
    for (int sub = 0; sub < 2; ++sub)
#pragma unroll
      for (int nt = 0; nt < 2; ++nt) s[sub][nt] = zero4;
    __builtin_amdgcn_s_setprio(1);
#pragma unroll
    for (int kk = 0; kk < 2; ++kk)
#pragma unroll
      for (int nt = 0; nt < 2; ++nt) {
        bf16x8 kf = *(const bf16x8*)&Kb[kk * 2048 + (kh * 32 + nt * 16 + l16) * 32 + quad * 8];
        s[0][nt] = __builtin_amdgcn_mfma_f32_16x16x32_bf16(kf, qf[0][kk], s[0][nt], 0, 0, 0);
        s[1][nt] = __builtin_amdgcn_mfma_f32_16x16x32_bf16(kf, qf[1][kk], s[1][nt], 0, 0, 0);
      }
    __builtin_amdgcn_s_setprio(0);

    // ---- p = 2^s (log2e pre-folded); packed cvt to bf16 A-frags; l partials ----
    s16x4 pf[2][2];
#pragma unroll
    for (int sub = 0; sub < 2; ++sub)
#pragma unroll
      for (int nt = 0; nt < 2; ++nt) {
        float p0 = exp2_fast(s[sub][nt][0]);
        float p1 = exp2_fast(s[sub][nt][1]);
        float p2 = exp2_fast(s[sub][nt][2]);
        float p3 = exp2_fast(s[sub][nt][3]);
        lsum[sub] += (p0 + p1) + (p2 + p3);
        union { unsigned int w[2]; s16x4 v; } u;
        u.w[0] = pk_bf16(p0, p1);
        u.w[1] = pk_bf16(p2, p3);
        pf[sub][nt] = u.v;
      }

    // ---- O += P V over this key-half; V-frag read once, used twice ----
    __builtin_amdgcn_s_setprio(1);
#pragma unroll
    for (int nt = 0; nt < 2; ++nt)
#pragma unroll
      for (int dt = 0; dt < 4; ++dt) {
        s16x4 vv = *(const s16x4*)&Vb[(dt * 16 + l16) * VS + kh * 32 + nt * 16 + quad * 4];
        o[0][dt] = __builtin_amdgcn_mfma_f32_16x16x16bf16_1k(pf[0][nt], vv, o[0][dt], 0, 0, 0);
        o[1][dt] = __builtin_amdgcn_mfma_f32_16x16x16bf16_1k(pf[1][nt], vv, o[1][dt], 0, 0, 0);
      }
    __builtin_amdgcn_s_setprio(0);

    // ---- sink next V's LDS writes after compute (vnext is compute-phase old) ----
    if (jt < 15) {
      unsigned short* vb = Vts + ((jt + 1) & 1) * (64 * VS);
#pragma unroll
      for (int e = 0; e < 8; ++e)
        vb[(vd0 + e) * VS + vn] = vnext[e];
    }
  }

  // ---- cross-wave key-half reduction: odd waves park O/l partials in LDS scratch ----
  // scratch aliases Ks+Vts: 4 qg x 64 lanes x 32 f32 = 32 KB (o) + 2 KB (l) = 34.8 KB
  __syncthreads();   // all K/V reads of jt=15 done; safe to overwrite lds
  float* sc = (float*)lds;
  float* scl = sc + 4 * 64 * 32;   // l-partials area
  if (kh) {
    float* dst = sc + (qg * 64 + lane) * 32;
#pragma unroll
    for (int sub = 0; sub < 2; ++sub)
#pragma unroll
      for (int dt = 0; dt < 4; ++dt)
        *(f32x4*)(dst + sub * 16 + dt * 4) = o[sub][dt];
    scl[(qg * 64 + lane) * 2 + 0] = lsum[0];
    scl[(qg * 64 + lane) * 2 + 1] = lsum[1];
  }
  __syncthreads();
  if (!kh) {
    const float* src = sc + (qg * 64 + lane) * 32;
#pragma unroll
    for (int sub = 0; sub < 2; ++sub)
#pragma unroll
      for (int dt = 0; dt < 4; ++dt)
        o[sub][dt] += *(const f32x4*)(src + sub * 16 + dt * 4);
    lsum[0] += scl[(qg * 64 + lane) * 2 + 0];
    lsum[1] += scl[(qg * 64 + lane) * 2 + 1];

    // ---- epilogue (even waves only): reduce l across quads, normalize, store ----
#pragma unroll
    for (int sub = 0; sub < 2; ++sub) {
      float l = lsum[sub];
      l += __shfl_xor(l, 16);
      l += __shfl_xor(l, 32);   // full sum for query l16 over all 64 keys
#pragma unroll
      for (int r = 0; r < 4; ++r) {
        float inv = 1.f / __shfl(l, quad * 4 + r);
        int row = rowQ0 + qg * 32 + sub * 16 + quad * 4 + r;
#pragma unroll
        for (int dt = 0; dt < 4; ++dt)
          out[(size_t)row * DIM + h * HD + dt * 16 + l16] = f2bf(o[sub][dt][r] * inv);
      }
    }
  }
}

extern "C" void kernel_launch(void* const* d_in, const int* in_sizes, int n_in,
                              void* d_out, int out_size, void* d_ws, size_t ws_size,
                              hipStream_t stream) {
  const float* x = (const float*)d_in[0];
  const float* w_qkv = (const float*)d_in[1];
  const float* w_proj = (const float*)d_in[2];
  const float* b_proj = (const float*)d_in[3];
  float* outp = (float*)d_out;

  unsigned short* xb = (unsigned short*)d_ws;                     // 8192*768 bf16 (reused as attn out)
  unsigned short* wqkvT = xb + (size_t)ROWS * DIM;                // [2304][768]
  unsigned short* wprojT = wqkvT + (size_t)QKVN * DIM;            // [768][768]
  unsigned short* qkvb = wprojT + (size_t)DIM * DIM;              // [8192][2304]
  unsigned short* attnb = xb;                                     // alias: xb dead after qkv gemm

  prep_kernel<<<dim3(6144 + 1728 + 576), 256, 0, stream>>>(x, xb, w_qkv, wqkvT, w_proj, wprojT);
  // qkv: 64 row-tiles (8/XCD) x 12 col-tiles of 192 = 768 blocks = exactly 3/CU
  gemm192<true, true><<<dim3(768), 256, 0, stream>>>(xb, wqkvT, qkvb, nullptr, ROWS, QKVN, DIM, 8);
  attn_kernel<<<dim3(8 * 96), 512, 0, stream>>>(qkvb, attnb);
  // proj: 64 row-tiles (8/XCD) x 12 col-tiles of 64 = 768 blocks (3/CU)
  gemm64_proj<<<dim3(768), 256, 0, stream>>>(attnb, wprojT, outp, b_proj, ROWS, DIM, DIM, 8);
}

// Round 13
// 181.429 us; speedup vs baseline: 1.1590x; 1.1590x over previous
//
#include <hip/hip_runtime.h>
#include <hip/hip_bf16.h>

#define NH 12
#define HD 64
#define SEQ 1024
#define BATCH 8
#define DIM 768
#define QKVN 2304
#define ROWS 8192   // BATCH*SEQ

typedef __bf16 bf16x8 __attribute__((ext_vector_type(8)));
typedef float f32x4 __attribute__((ext_vector_type(4)));
typedef unsigned short u16x8 __attribute__((ext_vector_type(8)));
typedef unsigned short u16x4 __attribute__((ext_vector_type(4)));
typedef short s16x4 __attribute__((ext_vector_type(4)));

__device__ __forceinline__ unsigned short f2bf(float f) {
  union { float f; unsigned int u; } c; c.f = f;
  unsigned int u = c.u;
  u += 0x7fffu + ((u >> 16) & 1u);   // RNE; inputs are normal floats
  return (unsigned short)(u >> 16);
}

__device__ __forceinline__ unsigned int pk_bf16(float a, float b) {
  // packed RNE f32->bf16 pair (v_cvt_pk_bf16_f32 on gfx950)
  union { __hip_bfloat162 h; unsigned int w; } u;
  u.h = __float22bfloat162_rn(float2{a, b});
  return u.w;
}

__device__ __forceinline__ float exp2_fast(float x) {
  // raw v_exp_f32 (computes 2^x). q-scale has log2e folded in at the qkv GEMM,
  // so softmax base-2 here is mathematically exact vs base-e.
  float r;
  asm("v_exp_f32 %0, %1" : "=v"(r) : "v"(x));
  return r;
}

__device__ __forceinline__ void gload_lds16(const unsigned short* g, unsigned short* l) {
  __builtin_amdgcn_global_load_lds(
      (const __attribute__((address_space(1))) void*)g,
      (__attribute__((address_space(3))) void*)l, 16, 0, 0);
}

// ---------------- fused prep: f32->bf16 cast + both weight transposes ----------------
__device__ __forceinline__ void tr_tile(const float* __restrict__ src, unsigned short* __restrict__ dst,
                                        int R, int C, int bx, int by, float tile[32][33]) {
  int tx = threadIdx.x & 31, ty = threadIdx.x >> 5;   // 32 x 8
  int c0 = bx * 32, r0 = by * 32;
#pragma unroll
  for (int i = 0; i < 4; ++i)
    tile[ty + i * 8][tx] = src[(size_t)(r0 + ty + i * 8) * C + c0 + tx];
  __syncthreads();
#pragma unroll
  for (int i = 0; i < 4; ++i)
    dst[(size_t)(c0 + ty + i * 8) * R + r0 + tx] = f2bf(tile[tx][ty + i * 8]);
}

__global__ void prep_kernel(const float* __restrict__ x, unsigned short* __restrict__ xb,
                            const float* __restrict__ w_qkv, unsigned short* __restrict__ wqkvT,
                            const float* __restrict__ w_proj, unsigned short* __restrict__ wprojT) {
  __shared__ float tile[32][33];
  int blk = blockIdx.x;
  if (blk < 6144) {
    int i = blk * 256 + threadIdx.x;   // n4 = 8192*768/4 = 1572864 = 6144*256 exactly
    float4 v = ((const float4*)x)[i];
    unsigned int lo = pk_bf16(v.x, v.y), hi = pk_bf16(v.z, v.w);
    union { unsigned int w[2]; u16x4 o; } u; u.w[0] = lo; u.w[1] = hi;
    ((u16x4*)xb)[i] = u.o;
  } else if (blk < 6144 + 1728) {
    int t = blk - 6144;                // w_qkv: 768x2304 -> 24 x 72 tiles
    tr_tile(w_qkv, wqkvT, DIM, QKVN, t % 72, t / 72, tile);
  } else {
    int t = blk - 6144 - 1728;         // w_proj: 768x768 -> 24 x 24 tiles
    tr_tile(w_proj, wprojT, DIM, DIM, t % 24, t / 24, tile);
  }
}

// ---------------- 128x192 bf16 GEMM (qkv), dbuf, 1 barrier/K-iter ----------------
// R1 retile: 768 blocks = exactly 3/CU. R7 lesson: the implicit wave overlap at 3
// blocks/CU IS the pipeline — counted-vmcnt/triple-buffer grafts regressed.
template <bool BF16_OUT, bool SCALE_Q>
__global__ __launch_bounds__(256, 3) void gemm192(
    const unsigned short* __restrict__ A, const unsigned short* __restrict__ BT,
    void* __restrict__ Cout, const float* __restrict__ bias,
    int M, int N, int K, int nbyXCD) {
  __shared__ unsigned short As[2][128 * 32];   // 8 KB / buf
  __shared__ unsigned short Bs[2][192 * 32];   // 12 KB / buf
  const int tid = threadIdx.x;
  const int wave = tid >> 6, lane = tid & 63, quad = lane >> 4, l16 = lane & 15;
  const int wm = wave >> 1, wn = wave & 1;     // 2x2 waves -> per-wave 64x96
  const int g = blockIdx.x & 7, bi = blockIdx.x >> 3;
  const int by = g * nbyXCD + (bi % nbyXCD);
  const int bx = bi / nbyXCD;
  const int bm = by * 128, bn = bx * 192;

  const int r0 = tid >> 2, kc0 = (tid & 3) * 8;
  const unsigned short* Ag = A + (size_t)(bm + r0) * K + kc0;
  const unsigned short* Bg = BT + (size_t)(bn + r0) * K + kc0;
  unsigned short* AsB = &As[0][0];
  unsigned short* BsB = &Bs[0][0];
  const int wdst = (tid & ~63) * 8;   // wave-uniform LDS chunk base (u16)

#define STAGE_G(kt, b) do {                                                   \
    int koff_ = (kt) * 32;                                                    \
    gload_lds16(Ag + koff_,                    AsB + (b) * 4096 + wdst);      \
    gload_lds16(Ag + koff_ + (size_t)64 * K,   AsB + (b) * 4096 + wdst + 2048);\
    gload_lds16(Bg + koff_,                    BsB + (b) * 6144 + wdst);      \
    gload_lds16(Bg + koff_ + (size_t)64 * K,   BsB + (b) * 6144 + wdst + 2048);\
    gload_lds16(Bg + koff_ + (size_t)128 * K,  BsB + (b) * 6144 + wdst + 4096);\
  } while (0)

  f32x4 zero4 = {0.f, 0.f, 0.f, 0.f};
  f32x4 acc[4][6];
#pragma unroll
  for (int i = 0; i < 4; ++i)
#pragma unroll
    for (int j = 0; j < 6; ++j) acc[i][j] = zero4;

  const int nkt = K >> 5;
  STAGE_G(0, 0);   // prologue: tile 0 -> buf 0
  for (int kt = 0; kt < nkt; ++kt) {
    __syncthreads();   // buf[kt&1] staged; reads of buf[(kt+1)&1] from kt-1 done
    if (kt + 1 < nkt) STAGE_G(kt + 1, (kt + 1) & 1);
    const unsigned short* Ab = AsB + (kt & 1) * 4096;
    const unsigned short* Bb = BsB + (kt & 1) * 6144;
    bf16x8 af[4], bf[6];
#pragma unroll
    for (int mt = 0; mt < 4; ++mt)
      af[mt] = *(const bf16x8*)&Ab[(wm * 64 + mt * 16 + l16) * 32 + quad * 8];
#pragma unroll
    for (int nt = 0; nt < 6; ++nt)
      bf[nt] = *(const bf16x8*)&Bb[(wn * 96 + nt * 16 + l16) * 32 + quad * 8];
#pragma unroll
    for (int mt = 0; mt < 4; ++mt)
#pragma unroll
      for (int nt = 0; nt < 6; ++nt)
        acc[mt][nt] = __builtin_amdgcn_mfma_f32_16x16x32_bf16(af[mt], bf[nt], acc[mt][nt], 0, 0, 0);
  }
#undef STAGE_G

#pragma unroll
  for (int mt = 0; mt < 4; ++mt)
#pragma unroll
    for (int nt = 0; nt < 6; ++nt) {
      int col = bn + wn * 96 + nt * 16 + l16;
      float bv = BF16_OUT ? 0.f : bias[col];
      // q-scale 0.125 with log2e folded in (attn uses base-2 exp; exact fold)
      float scl = (SCALE_Q && col < DIM) ? 0.18033688011112042f : 1.0f;
#pragma unroll
      for (int r = 0; r < 4; ++r) {
        int row = bm + wm * 64 + mt * 16 + quad * 4 + r;
        float v = acc[mt][nt][r];
        if (BF16_OUT)
          ((unsigned short*)Cout)[(size_t)row * N + col] = f2bf(v * scl);
        else
          ((float*)Cout)[(size_t)row * N + col] = v + bv;
      }
    }
}

// ---------------- 128x64 bf16 GEMM for proj, BK=64 (R6-verified config) ----------------
// Chunk-XOR swizzle both sides. LDS 48 KB -> 3 blocks/CU. (256,4) caps VGPR at 128.
__global__ __launch_bounds__(256, 4) void gemm64_proj(
    const unsigned short* __restrict__ A, const unsigned short* __restrict__ BT,
    float* __restrict__ Cout, const float* __restrict__ bias,
    int M, int N, int K, int nbyXCD) {
  __shared__ unsigned short As[2][128 * 64];   // 16 KB / buf
  __shared__ unsigned short Bs[2][64 * 64];    // 8 KB / buf
  const int tid = threadIdx.x;
  const int wave = tid >> 6, lane = tid & 63, quad = lane >> 4, l16 = lane & 15;
  const int g = blockIdx.x & 7, bi = blockIdx.x >> 3;
  const int by = g * nbyXCD + (bi % nbyXCD);
  const int bx = bi / nbyXCD;
  const int bm = by * 128, bn = bx * 64;

  const int r0 = tid >> 3;                       // 0..31 (row within a 32-row call)
  const int csw = ((tid & 7) ^ (r0 & 7)) * 8;    // XOR-swizzled source col chunk
  const unsigned short* Ag = A + (size_t)(bm + r0) * K + csw;
  const unsigned short* Bg = BT + (size_t)(bn + r0) * K + csw;
  unsigned short* AsB = &As[0][0];
  unsigned short* BsB = &Bs[0][0];
  const int wdst = (tid & ~63) * 8;   // wave-uniform; per-lane dest = tid*8 (linear)

#define STAGE_P(kt, b) do {                                                     \
    int koff_ = (kt) * 64;                                                      \
    gload_lds16(Ag + koff_,                   AsB + (b) * 8192 + wdst);         \
    gload_lds16(Ag + koff_ + (size_t)32 * K,  AsB + (b) * 8192 + wdst + 2048);  \
    gload_lds16(Ag + koff_ + (size_t)64 * K,  AsB + (b) * 8192 + wdst + 4096);  \
    gload_lds16(Ag + koff_ + (size_t)96 * K,  AsB + (b) * 8192 + wdst + 6144);  \
    gload_lds16(Bg + koff_,                   BsB + (b) * 4096 + wdst);         \
    gload_lds16(Bg + koff_ + (size_t)32 * K,  BsB + (b) * 4096 + wdst + 2048);  \
  } while (0)

  f32x4 zero4 = {0.f, 0.f, 0.f, 0.f};
  f32x4 acc[2][4];
#pragma unroll
  for (int i = 0; i < 2; ++i)
#pragma unroll
    for (int j = 0; j < 4; ++j) acc[i][j] = zero4;

  const int nkt = K >> 6;   // 12
  STAGE_P(0, 0);
  for (int kt = 0; kt < nkt; ++kt) {
    __syncthreads();
    if (kt + 1 < nkt) STAGE_P(kt + 1, (kt + 1) & 1);
    const unsigned short* Ab = AsB + (kt & 1) * 8192;
    const unsigned short* Bb = BsB + (kt & 1) * 4096;
#pragma unroll
    for (int kk = 0; kk < 2; ++kk) {
      const int pc = ((kk * 4 + quad) ^ (l16 & 7)) * 8;   // physical chunk (swizzled)
      bf16x8 af[2], bf[4];
#pragma unroll
      for (int mt = 0; mt < 2; ++mt)
        af[mt] = *(const bf16x8*)&Ab[(wave * 32 + mt * 16 + l16) * 64 + pc];
#pragma unroll
      for (int nt = 0; nt < 4; ++nt)
        bf[nt] = *(const bf16x8*)&Bb[(nt * 16 + l16) * 64 + pc];
#pragma unroll
      for (int mt = 0; mt < 2; ++mt)
#pragma unroll
        for (int nt = 0; nt < 4; ++nt)
          acc[mt][nt] = __builtin_amdgcn_mfma_f32_16x16x32_bf16(af[mt], bf[nt], acc[mt][nt], 0, 0, 0);
    }
  }
#undef STAGE_P

#pragma unroll
  for (int mt = 0; mt < 2; ++mt)
#pragma unroll
    for (int nt = 0; nt < 4; ++nt) {
      int col = bn + nt * 16 + l16;
      float bv = bias[col];
#pragma unroll
      for (int r = 0; r < 4; ++r) {
        int row = bm + wave * 32 + mt * 16 + quad * 4 + r;
        Cout[(size_t)row * N + col] = acc[mt][nt][r] + bv;
      }
    }
}

// ---------------- flash attention: Q-tile 128 (8 waves), KV-tile 64 ----------------
// R12: REVERT to R6-exact (45.0 us, verified across 3 runs). The attn structure's
// feasible corner: R2 (fat waves, fewer: 55.5), R4 (1 block/CU: 59.5), R8
// (reorder: 51.4), R11 (fat waves at full occupancy: VGPR spills, 84.0) — every
// perturbation direction measured and regressed. LDS-traffic ~ 1/(queries/wave),
// registers ~ queries/wave, occupancy caps registers: this config is the corner.
#define VS 76   // Vts row stride (u16)
__global__ __launch_bounds__(512, 6) void attn_kernel(
    const unsigned short* __restrict__ qkv, unsigned short* __restrict__ out) {
  __shared__ unsigned short Ks[2][64 * 64];     // [kk][n][32] split layout per buffer, 8 KB each
  __shared__ unsigned short Vts[2][64 * VS];    // V^T [d][n], 9.5 KB each

  const int tid = threadIdx.x;
  const int wave = tid >> 6, lane = tid & 63, quad = lane >> 4, l16 = lane & 15;
  // XCD-locality swizzle: all 8 q-tiles of one (b,h) share id%8 -> same XCD
  const int x = blockIdx.x;
  const int qt = (x >> 3) & 7;
  const int bh = (x & 7) + 8 * (x >> 6);
  const int b = bh / NH, h = bh % NH;
  const int qcol = h * HD, kcol = DIM + h * HD, vcol = 2 * DIM + h * HD;
  const int rowQ0 = b * SEQ + qt * 128;
  const int rowKV0 = b * SEQ;

  // staging index precompute
  const int kk_s = tid >> 8, rem_s = tid & 255, n_s = rem_s >> 2, kc_s = rem_s & 3;
  const unsigned short* kgp = qkv + (size_t)(rowKV0 + n_s) * QKVN + kcol + kk_s * 32 + kc_s * 8;
  unsigned short* klp = &Ks[0][0] + (tid & ~63) * 8;   // wave-uniform base (u16 units)
  const int vn = tid & 63, vd0 = (tid >> 6) * 8;
  const unsigned short* vgp = qkv + (size_t)(rowKV0 + vn) * QKVN + vcol + vd0;

  // ---- Q fragments straight from global ----
  bf16x8 qf[2];
  {
    const unsigned short* qp = qkv + (size_t)(rowQ0 + wave * 16 + l16) * QKVN + qcol + quad * 8;
    qf[0] = *(const bf16x8*)qp;
    qf[1] = *(const bf16x8*)(qp + 32);
  }

  // ---- prologue: stage tile 0 into buffer 0 ----
  gload_lds16(kgp, klp);
  {
    u16x8 v0 = *(const u16x8*)vgp;
    unsigned short* vb = &Vts[0][0];
#pragma unroll
    for (int e = 0; e < 8; ++e)
      vb[(vd0 + e) * VS + vn] = v0[e];
  }

  f32x4 zero4 = {0.f, 0.f, 0.f, 0.f};
  f32x4 o[4];
#pragma unroll
  for (int dt = 0; dt < 4; ++dt) o[dt] = zero4;
  float lsum = 0.f;

  for (int jt = 0; jt < 16; ++jt) {
    __syncthreads();   // drains K-DMA(jt) + vload(jt): both one compute phase old
    u16x8 vnext;
    if (jt < 15) {
      gload_lds16(kgp + (size_t)(jt + 1) * 64 * QKVN, klp + ((jt + 1) & 1) * 4096);
      vnext = *(const u16x8*)(vgp + (size_t)(jt + 1) * 64 * QKVN);
    }

    const unsigned short* Kb = &Ks[jt & 1][0];
    const unsigned short* Vb = &Vts[jt & 1][0];

    // ---- S^T = K Q^T : rows=keys, cols=queries ----
    f32x4 s[4];
#pragma unroll
    for (int nt = 0; nt < 4; ++nt) s[nt] = zero4;
    __builtin_amdgcn_s_setprio(1);
#pragma unroll
    for (int kk = 0; kk < 2; ++kk)
#pragma unroll
      for (int nt = 0; nt < 4; ++nt) {
        bf16x8 kf = *(const bf16x8*)&Kb[kk * 2048 + (nt * 16 + l16) * 32 + quad * 8];
        s[nt] = __builtin_amdgcn_mfma_f32_16x16x32_bf16(kf, qf[kk], s[nt], 0, 0, 0);
      }
    __builtin_amdgcn_s_setprio(0);

    // ---- p = 2^s (log2e pre-folded); packed cvt to bf16 A-frags; l partials ----
    s16x4 pf[4];
#pragma unroll
    for (int nt = 0; nt < 4; ++nt) {
      float p0 = exp2_fast(s[nt][0]);
      float p1 = exp2_fast(s[nt][1]);
      float p2 = exp2_fast(s[nt][2]);
      float p3 = exp2_fast(s[nt][3]);
      lsum += (p0 + p1) + (p2 + p3);
      union { unsigned int w[2]; s16x4 v; } u;
      u.w[0] = pk_bf16(p0, p1);
      u.w[1] = pk_bf16(p2, p3);
      pf[nt] = u.v;
    }

    // ---- O += P V  (P^T regs as A-frag, V^T LDS as B-frag, K=16 chunks) ----
    __builtin_amdgcn_s_setprio(1);
#pragma unroll
    for (int nt = 0; nt < 4; ++nt)
#pragma unroll
      for (int dt = 0; dt < 4; ++dt) {
        s16x4 vv = *(const s16x4*)&Vb[(dt * 16 + l16) * VS + nt * 16 + quad * 4];
        o[dt] = __builtin_amdgcn_mfma_f32_16x16x16bf16_1k(pf[nt], vv, o[dt], 0, 0, 0);
      }
    __builtin_amdgcn_s_setprio(0);

    // ---- sink next V's LDS writes after compute (vnext is compute-phase old) ----
    if (jt < 15) {
      unsigned short* vb = &Vts[(jt + 1) & 1][0];
#pragma unroll
      for (int e = 0; e < 8; ++e)
        vb[(vd0 + e) * VS + vn] = vnext[e];
    }
  }

  // ---- epilogue: reduce l across quads, redistribute, normalize, store ----
  float l = lsum;
  l += __shfl_xor(l, 16);
  l += __shfl_xor(l, 32);   // full sum for query l16
#pragma unroll
  for (int r = 0; r < 4; ++r) {
    float inv = 1.f / __shfl(l, quad * 4 + r);
    int row = rowQ0 + wave * 16 + quad * 4 + r;
#pragma unroll
    for (int dt = 0; dt < 4; ++dt)
      out[(size_t)row * DIM + h * HD + dt * 16 + l16] = f2bf(o[dt][r] * inv);
  }
}

extern "C" void kernel_launch(void* const* d_in, const int* in_sizes, int n_in,
                              void* d_out, int out_size, void* d_ws, size_t ws_size,
                              hipStream_t stream) {
  const float* x = (const float*)d_in[0];
  const float* w_qkv = (const float*)d_in[1];
  const float* w_proj = (const float*)d_in[2];
  const float* b_proj = (const float*)d_in[3];
  float* outp = (float*)d_out;

  unsigned short* xb = (unsigned short*)d_ws;                     // 8192*768 bf16 (reused as attn out)
  unsigned short* wqkvT = xb + (size_t)ROWS * DIM;                // [2304][768]
  unsigned short* wprojT = wqkvT + (size_t)QKVN * DIM;            // [768][768]
  unsigned short* qkvb = wprojT + (size_t)DIM * DIM;              // [8192][2304]
  unsigned short* attnb = xb;                                     // alias: xb dead after qkv gemm

  prep_kernel<<<dim3(6144 + 1728 + 576), 256, 0, stream>>>(x, xb, w_qkv, wqkvT, w_proj, wprojT);
  // qkv: 64 row-tiles (8/XCD) x 12 col-tiles of 192 = 768 blocks = exactly 3/CU
  gemm192<true, true><<<dim3(768), 256, 0, stream>>>(xb, wqkvT, qkvb, nullptr, ROWS, QKVN, DIM, 8);
  attn_kernel<<<dim3(8 * 96), 512, 0, stream>>>(qkvb, attnb);
  // proj: 64 row-tiles (8/XCD) x 12 col-tiles of 64 = 768 blocks (3/CU)
  gemm64_proj<<<dim3(768), 256, 0, stream>>>(attnb, wprojT, outp, b_proj, ROWS, DIM, DIM, 8);
}

// Round 14
// 179.005 us; speedup vs baseline: 1.1747x; 1.0135x over previous
//
#include <hip/hip_runtime.h>
#include <hip/hip_bf16.h>

#define NH 12
#define HD 64
#define SEQ 1024
#define BATCH 8
#define DIM 768
#define QKVN 2304
#define ROWS 8192   // BATCH*SEQ

typedef __bf16 bf16x8 __attribute__((ext_vector_type(8)));
typedef float f32x4 __attribute__((ext_vector_type(4)));
typedef unsigned short u16x8 __attribute__((ext_vector_type(8)));
typedef unsigned short u16x4 __attribute__((ext_vector_type(4)));
typedef short s16x4 __attribute__((ext_vector_type(4)));

__device__ __forceinline__ unsigned short f2bf(float f) {
  union { float f; unsigned int u; } c; c.f = f;
  unsigned int u = c.u;
  u += 0x7fffu + ((u >> 16) & 1u);   // RNE; inputs are normal floats
  return (unsigned short)(u >> 16);
}

__device__ __forceinline__ unsigned int pk_bf16(float a, float b) {
  // packed RNE f32->bf16 pair (v_cvt_pk_bf16_f32 on gfx950)
  union { __hip_bfloat162 h; unsigned int w; } u;
  u.h = __float22bfloat162_rn(float2{a, b});
  return u.w;
}

__device__ __forceinline__ float exp2_fast(float x) {
  // raw v_exp_f32 (computes 2^x). q-scale has log2e folded in at the qkv GEMM,
  // so softmax base-2 here is mathematically exact vs base-e.
  float r;
  asm("v_exp_f32 %0, %1" : "=v"(r) : "v"(x));
  return r;
}

__device__ __forceinline__ void gload_lds16(const unsigned short* g, unsigned short* l) {
  __builtin_amdgcn_global_load_lds(
      (const __attribute__((address_space(1))) void*)g,
      (__attribute__((address_space(3))) void*)l, 16, 0, 0);
}

// ---------------- fused prep: f32->bf16 cast + both weight transposes ----------------
__device__ __forceinline__ void tr_tile(const float* __restrict__ src, unsigned short* __restrict__ dst,
                                        int R, int C, int bx, int by, float tile[32][33]) {
  int tx = threadIdx.x & 31, ty = threadIdx.x >> 5;   // 32 x 8
  int c0 = bx * 32, r0 = by * 32;
#pragma unroll
  for (int i = 0; i < 4; ++i)
    tile[ty + i * 8][tx] = src[(size_t)(r0 + ty + i * 8) * C + c0 + tx];
  __syncthreads();
#pragma unroll
  for (int i = 0; i < 4; ++i)
    dst[(size_t)(c0 + ty + i * 8) * R + r0 + tx] = f2bf(tile[tx][ty + i * 8]);
}

__global__ void prep_kernel(const float* __restrict__ x, unsigned short* __restrict__ xb,
                            const float* __restrict__ w_qkv, unsigned short* __restrict__ wqkvT,
                            const float* __restrict__ w_proj, unsigned short* __restrict__ wprojT) {
  __shared__ float tile[32][33];
  int blk = blockIdx.x;
  if (blk < 6144) {
    int i = blk * 256 + threadIdx.x;   // n4 = 8192*768/4 = 1572864 = 6144*256 exactly
    float4 v = ((const float4*)x)[i];
    unsigned int lo = pk_bf16(v.x, v.y), hi = pk_bf16(v.z, v.w);
    union { unsigned int w[2]; u16x4 o; } u; u.w[0] = lo; u.w[1] = hi;
    ((u16x4*)xb)[i] = u.o;
  } else if (blk < 6144 + 1728) {
    int t = blk - 6144;                // w_qkv: 768x2304 -> 24 x 72 tiles
    tr_tile(w_qkv, wqkvT, DIM, QKVN, t % 72, t / 72, tile);
  } else {
    int t = blk - 6144 - 1728;         // w_proj: 768x768 -> 24 x 24 tiles
    tr_tile(w_proj, wprojT, DIM, DIM, t % 24, t / 24, tile);
  }
}

// ---------------- 128x192 bf16 GEMM (qkv), dbuf, 1 barrier/K-iter ----------------
// R1 retile: 768 blocks = exactly 3/CU. R7 lesson: the implicit wave overlap at 3
// blocks/CU IS the pipeline — counted-vmcnt/triple-buffer grafts regressed.
template <bool BF16_OUT, bool SCALE_Q>
__global__ __launch_bounds__(256, 3) void gemm192(
    const unsigned short* __restrict__ A, const unsigned short* __restrict__ BT,
    void* __restrict__ Cout, const float* __restrict__ bias,
    int M, int N, int K, int nbyXCD) {
  __shared__ unsigned short As[2][128 * 32];   // 8 KB / buf
  __shared__ unsigned short Bs[2][192 * 32];   // 12 KB / buf
  const int tid = threadIdx.x;
  const int wave = tid >> 6, lane = tid & 63, quad = lane >> 4, l16 = lane & 15;
  const int wm = wave >> 1, wn = wave & 1;     // 2x2 waves -> per-wave 64x96
  const int g = blockIdx.x & 7, bi = blockIdx.x >> 3;
  const int by = g * nbyXCD + (bi % nbyXCD);
  const int bx = bi / nbyXCD;
  const int bm = by * 128, bn = bx * 192;

  const int r0 = tid >> 2, kc0 = (tid & 3) * 8;
  const unsigned short* Ag = A + (size_t)(bm + r0) * K + kc0;
  const unsigned short* Bg = BT + (size_t)(bn + r0) * K + kc0;
  unsigned short* AsB = &As[0][0];
  unsigned short* BsB = &Bs[0][0];
  const int wdst = (tid & ~63) * 8;   // wave-uniform LDS chunk base (u16)

#define STAGE_G(kt, b) do {                                                   \
    int koff_ = (kt) * 32;                                                    \
    gload_lds16(Ag + koff_,                    AsB + (b) * 4096 + wdst);      \
    gload_lds16(Ag + koff_ + (size_t)64 * K,   AsB + (b) * 4096 + wdst + 2048);\
    gload_lds16(Bg + koff_,                    BsB + (b) * 6144 + wdst);      \
    gload_lds16(Bg + koff_ + (size_t)64 * K,   BsB + (b) * 6144 + wdst + 2048);\
    gload_lds16(Bg + koff_ + (size_t)128 * K,  BsB + (b) * 6144 + wdst + 4096);\
  } while (0)

  f32x4 zero4 = {0.f, 0.f, 0.f, 0.f};
  f32x4 acc[4][6];
#pragma unroll
  for (int i = 0; i < 4; ++i)
#pragma unroll
    for (int j = 0; j < 6; ++j) acc[i][j] = zero4;

  const int nkt = K >> 5;
  STAGE_G(0, 0);   // prologue: tile 0 -> buf 0
  for (int kt = 0; kt < nkt; ++kt) {
    __syncthreads();   // buf[kt&1] staged; reads of buf[(kt+1)&1] from kt-1 done
    if (kt + 1 < nkt) STAGE_G(kt + 1, (kt + 1) & 1);
    const unsigned short* Ab = AsB + (kt & 1) * 4096;
    const unsigned short* Bb = BsB + (kt & 1) * 6144;
    bf16x8 af[4], bf[6];
#pragma unroll
    for (int mt = 0; mt < 4; ++mt)
      af[mt] = *(const bf16x8*)&Ab[(wm * 64 + mt * 16 + l16) * 32 + quad * 8];
#pragma unroll
    for (int nt = 0; nt < 6; ++nt)
      bf[nt] = *(const bf16x8*)&Bb[(wn * 96 + nt * 16 + l16) * 32 + quad * 8];
#pragma unroll
    for (int mt = 0; mt < 4; ++mt)
#pragma unroll
      for (int nt = 0; nt < 6; ++nt)
        acc[mt][nt] = __builtin_amdgcn_mfma_f32_16x16x32_bf16(af[mt], bf[nt], acc[mt][nt], 0, 0, 0);
  }
#undef STAGE_G

#pragma unroll
  for (int mt = 0; mt < 4; ++mt)
#pragma unroll
    for (int nt = 0; nt < 6; ++nt) {
      int col = bn + wn * 96 + nt * 16 + l16;
      float bv = BF16_OUT ? 0.f : bias[col];
      // q-scale 0.125 with log2e folded in (attn uses base-2 exp; exact fold)
      float scl = (SCALE_Q && col < DIM) ? 0.18033688011112042f : 1.0f;
#pragma unroll
      for (int r = 0; r < 4; ++r) {
        int row = bm + wm * 64 + mt * 16 + quad * 4 + r;
        float v = acc[mt][nt][r];
        if (BF16_OUT)
          ((unsigned short*)Cout)[(size_t)row * N + col] = f2bf(v * scl);
        else
          ((float*)Cout)[(size_t)row * N + col] = v + bv;
      }
    }
}

// ---------------- 128x64 bf16 GEMM for proj, BK=64 (R6-verified config) ----------------
// Chunk-XOR swizzle both sides. LDS 48 KB -> 3 blocks/CU. (256,4) caps VGPR at 128.
__global__ __launch_bounds__(256, 4) void gemm64_proj(
    const unsigned short* __restrict__ A, const unsigned short* __restrict__ BT,
    float* __restrict__ Cout, const float* __restrict__ bias,
    int M, int N, int K, int nbyXCD) {
  __shared__ unsigned short As[2][128 * 64];   // 16 KB / buf
  __shared__ unsigned short Bs[2][64 * 64];    // 8 KB / buf
  const int tid = threadIdx.x;
  const int wave = tid >> 6, lane = tid & 63, quad = lane >> 4, l16 = lane & 15;
  const int g = blockIdx.x & 7, bi = blockIdx.x >> 3;
  const int by = g * nbyXCD + (bi % nbyXCD);
  const int bx = bi / nbyXCD;
  const int bm = by * 128, bn = bx * 64;

  const int r0 = tid >> 3;                       // 0..31 (row within a 32-row call)
  const int csw = ((tid & 7) ^ (r0 & 7)) * 8;    // XOR-swizzled source col chunk
  const unsigned short* Ag = A + (size_t)(bm + r0) * K + csw;
  const unsigned short* Bg = BT + (size_t)(bn + r0) * K + csw;
  unsigned short* AsB = &As[0][0];
  unsigned short* BsB = &Bs[0][0];
  const int wdst = (tid & ~63) * 8;   // wave-uniform; per-lane dest = tid*8 (linear)

#define STAGE_P(kt, b) do {                                                     \
    int koff_ = (kt) * 64;                                                      \
    gload_lds16(Ag + koff_,                   AsB + (b) * 8192 + wdst);         \
    gload_lds16(Ag + koff_ + (size_t)32 * K,  AsB + (b) * 8192 + wdst + 2048);  \
    gload_lds16(Ag + koff_ + (size_t)64 * K,  AsB + (b) * 8192 + wdst + 4096);  \
    gload_lds16(Ag + koff_ + (size_t)96 * K,  AsB + (b) * 8192 + wdst + 6144);  \
    gload_lds16(Bg + koff_,                   BsB + (b) * 4096 + wdst);         \
    gload_lds16(Bg + koff_ + (size_t)32 * K,  BsB + (b) * 4096 + wdst + 2048);  \
  } while (0)

  f32x4 zero4 = {0.f, 0.f, 0.f, 0.f};
  f32x4 acc[2][4];
#pragma unroll
  for (int i = 0; i < 2; ++i)
#pragma unroll
    for (int j = 0; j < 4; ++j) acc[i][j] = zero4;

  const int nkt = K >> 6;   // 12
  STAGE_P(0, 0);
  for (int kt = 0; kt < nkt; ++kt) {
    __syncthreads();
    if (kt + 1 < nkt) STAGE_P(kt + 1, (kt + 1) & 1);
    const unsigned short* Ab = AsB + (kt & 1) * 8192;
    const unsigned short* Bb = BsB + (kt & 1) * 4096;
#pragma unroll
    for (int kk = 0; kk < 2; ++kk) {
      const int pc = ((kk * 4 + quad) ^ (l16 & 7)) * 8;   // physical chunk (swizzled)
      bf16x8 af[2], bf[4];
#pragma unroll
      for (int mt = 0; mt < 2; ++mt)
        af[mt] = *(const bf16x8*)&Ab[(wave * 32 + mt * 16 + l16) * 64 + pc];
#pragma unroll
      for (int nt = 0; nt < 4; ++nt)
        bf[nt] = *(const bf16x8*)&Bb[(nt * 16 + l16) * 64 + pc];
#pragma unroll
      for (int mt = 0; mt < 2; ++mt)
#pragma unroll
        for (int nt = 0; nt < 4; ++nt)
          acc[mt][nt] = __builtin_amdgcn_mfma_f32_16x16x32_bf16(af[mt], bf[nt], acc[mt][nt], 0, 0, 0);
    }
  }
#undef STAGE_P

#pragma unroll
  for (int mt = 0; mt < 2; ++mt)
#pragma unroll
    for (int nt = 0; nt < 4; ++nt) {
      int col = bn + nt * 16 + l16;
      float bv = bias[col];
#pragma unroll
      for (int r = 0; r < 4; ++r) {
        int row = bm + wave * 32 + mt * 16 + quad * 4 + r;
        Cout[(size_t)row * N + col] = acc[mt][nt][r] + bv;
      }
    }
}

// ---------------- flash attention: Q-tile 128, KEY-SPLIT 8 waves, KV-tile 64 ----------------
// R13: R11's key-split was CORRECTNESS-VERIFIED but spilled at (512,6)'s ~85-reg
// cap (FETCH/WRITE +37/+34 MB scratch traffic, 84 us). One-token fix: (512,4)
// lifts the cap; 2 blocks/CU = 16 waves. Key-split wave chain length == baseline
// wave (8 QK MFMA + 16 exp + 16 PV — identical counts) but HALF the LDS reads
// (4 b128 + 8 b64): per-CU LDS/jt ~1900 cy vs baseline ~6500. Tests the R11 LDS
// model with the spill confound removed. Decisive counter: FETCH/WRITE back to
// 18.5/12.3 MB.
#define VS 76   // Vts row stride (u16)
__global__ __launch_bounds__(512, 4) void attn_kernel(
    const unsigned short* __restrict__ qkv, unsigned short* __restrict__ out) {
  __shared__ unsigned short lds[2 * 64 * 64 + 2 * 64 * VS];   // Ks | Vts, 35840 B
  unsigned short* Ks = lds;                    // [2][64*64], [kk][n][32] split layout
  unsigned short* Vts = lds + 2 * 64 * 64;     // [2][64*VS], V^T [d][n]

  const int tid = threadIdx.x;
  const int wave = tid >> 6, lane = tid & 63, quad = lane >> 4, l16 = lane & 15;
  const int qg = wave >> 1, kh = wave & 1;     // q-group 0..3, key-half 0..1
  // XCD-locality swizzle: all 8 q-tiles of one (b,h) share id%8 -> same XCD
  const int x = blockIdx.x;
  const int qt = (x >> 3) & 7;
  const int bh = (x & 7) + 8 * (x >> 6);
  const int b = bh / NH, h = bh % NH;
  const int qcol = h * HD, kcol = DIM + h * HD, vcol = 2 * DIM + h * HD;
  const int rowQ0 = b * SEQ + qt * 128;
  const int rowKV0 = b * SEQ;

  // staging index precompute (cooperative over the FULL 64-key tile — unchanged)
  const int kk_s = tid >> 8, rem_s = tid & 255, n_s = rem_s >> 2, kc_s = rem_s & 3;
  const unsigned short* kgp = qkv + (size_t)(rowKV0 + n_s) * QKVN + kcol + kk_s * 32 + kc_s * 8;
  unsigned short* klp = Ks + (tid & ~63) * 8;   // wave-uniform base (u16 units)
  const int vn = tid & 63, vd0 = (tid >> 6) * 8;
  const unsigned short* vgp = qkv + (size_t)(rowKV0 + vn) * QKVN + vcol + vd0;

  // ---- Q fragments straight from global: 2 sub-tiles of 16 q-rows per wave ----
  bf16x8 qf[2][2];
#pragma unroll
  for (int sub = 0; sub < 2; ++sub) {
    const unsigned short* qp = qkv + (size_t)(rowQ0 + qg * 32 + sub * 16 + l16) * QKVN + qcol + quad * 8;
    qf[sub][0] = *(const bf16x8*)qp;
    qf[sub][1] = *(const bf16x8*)(qp + 32);
  }

  // ---- prologue: stage tile 0 into buffer 0 ----
  gload_lds16(kgp, klp);
  {
    u16x8 v0 = *(const u16x8*)vgp;
    unsigned short* vb = Vts;
#pragma unroll
    for (int e = 0; e < 8; ++e)
      vb[(vd0 + e) * VS + vn] = v0[e];
  }

  f32x4 zero4 = {0.f, 0.f, 0.f, 0.f};
  f32x4 o[2][4];
#pragma unroll
  for (int sub = 0; sub < 2; ++sub)
#pragma unroll
    for (int dt = 0; dt < 4; ++dt) o[sub][dt] = zero4;
  float lsum[2] = {0.f, 0.f};

  for (int jt = 0; jt < 16; ++jt) {
    __syncthreads();   // drains K-DMA(jt) + vload(jt): both one compute phase old
    u16x8 vnext;
    if (jt < 15) {
      gload_lds16(kgp + (size_t)(jt + 1) * 64 * QKVN, klp + ((jt + 1) & 1) * 4096);
      vnext = *(const u16x8*)(vgp + (size_t)(jt + 1) * 64 * QKVN);
    }

    const unsigned short* Kb = Ks + (jt & 1) * 4096;
    const unsigned short* Vb = Vts + (jt & 1) * (64 * VS);

    // ---- S^T = K Q^T on this wave's 32-key half; K-frag read once, used twice ----
    f32x4 s[2][2];
#pragma unroll
    for (int sub = 0; sub < 2; ++sub)
#pragma unroll
      for (int nt = 0; nt < 2; ++nt) s[sub][nt] = zero4;
    __builtin_amdgcn_s_setprio(1);
#pragma unroll
    for (int kk = 0; kk < 2; ++kk)
#pragma unroll
      for (int nt = 0; nt < 2; ++nt) {
        bf16x8 kf = *(const bf16x8*)&Kb[kk * 2048 + (kh * 32 + nt * 16 + l16) * 32 + quad * 8];
        s[0][nt] = __builtin_amdgcn_mfma_f32_16x16x32_bf16(kf, qf[0][kk], s[0][nt], 0, 0, 0);
        s[1][nt] = __builtin_amdgcn_mfma_f32_16x16x32_bf16(kf, qf[1][kk], s[1][nt], 0, 0, 0);
      }
    __builtin_amdgcn_s_setprio(0);

    // ---- p = 2^s (log2e pre-folded); packed cvt to bf16 A-frags; l partials ----
    s16x4 pf[2][2];
#pragma unroll
    for (int sub = 0; sub < 2; ++sub)
#pragma unroll
      for (int nt = 0; nt < 2; ++nt) {
        float p0 = exp2_fast(s[sub][nt][0]);
        float p1 = exp2_fast(s[sub][nt][1]);
        float p2 = exp2_fast(s[sub][nt][2]);
        float p3 = exp2_fast(s[sub][nt][3]);
        lsum[sub] += (p0 + p1) + (p2 + p3);
        union { unsigned int w[2]; s16x4 v; } u;
        u.w[0] = pk_bf16(p0, p1);
        u.w[1] = pk_bf16(p2, p3);
        pf[sub][nt] = u.v;
      }

    // ---- O += P V over this key-half; V-frag read once, used twice ----
    __builtin_amdgcn_s_setprio(1);
#pragma unroll
    for (int nt = 0; nt < 2; ++nt)
#pragma unroll
      for (int dt = 0; dt < 4; ++dt) {
        s16x4 vv = *(const s16x4*)&Vb[(dt * 16 + l16) * VS + kh * 32 + nt * 16 + quad * 4];
        o[0][dt] = __builtin_amdgcn_mfma_f32_16x16x16bf16_1k(pf[0][nt], vv, o[0][dt], 0, 0, 0);
        o[1][dt] = __builtin_amdgcn_mfma_f32_16x16x16bf16_1k(pf[1][nt], vv, o[1][dt], 0, 0, 0);
      }
    __builtin_amdgcn_s_setprio(0);

    // ---- sink next V's LDS writes after compute (vnext is compute-phase old) ----
    if (jt < 15) {
      unsigned short* vb = Vts + ((jt + 1) & 1) * (64 * VS);
#pragma unroll
      for (int e = 0; e < 8; ++e)
        vb[(vd0 + e) * VS + vn] = vnext[e];
    }
  }

  // ---- cross-wave key-half reduction: odd waves park O/l partials in LDS scratch ----
  // scratch aliases Ks+Vts: 4 qg x 64 lanes x 32 f32 = 32 KB (o) + 2 KB (l) = 34.8 KB
  __syncthreads();   // all K/V reads of jt=15 done; safe to overwrite lds
  float* sc = (float*)lds;
  float* scl = sc + 4 * 64 * 32;   // l-partials area
  if (kh) {
    float* dst = sc + (qg * 64 + lane) * 32;
#pragma unroll
    for (int sub = 0; sub < 2; ++sub)
#pragma unroll
      for (int dt = 0; dt < 4; ++dt)
        *(f32x4*)(dst + sub * 16 + dt * 4) = o[sub][dt];
    scl[(qg * 64 + lane) * 2 + 0] = lsum[0];
    scl[(qg * 64 + lane) * 2 + 1] = lsum[1];
  }
  __syncthreads();
  if (!kh) {
    const float* src = sc + (qg * 64 + lane) * 32;
#pragma unroll
    for (int sub = 0; sub < 2; ++sub)
#pragma unroll
      for (int dt = 0; dt < 4; ++dt)
        o[sub][dt] += *(const f32x4*)(src + sub * 16 + dt * 4);
    lsum[0] += scl[(qg * 64 + lane) * 2 + 0];
    lsum[1] += scl[(qg * 64 + lane) * 2 + 1];

    // ---- epilogue (even waves only): reduce l across quads, normalize, store ----
#pragma unroll
    for (int sub = 0; sub < 2; ++sub) {
      float l = lsum[sub];
      l += __shfl_xor(l, 16);
      l += __shfl_xor(l, 32);   // full sum for query l16 over all 64 keys
#pragma unroll
      for (int r = 0; r < 4; ++r) {
        float inv = 1.f / __shfl(l, quad * 4 + r);
        int row = rowQ0 + qg * 32 + sub * 16 + quad * 4 + r;
#pragma unroll
        for (int dt = 0; dt < 4; ++dt)
          out[(size_t)row * DIM + h * HD + dt * 16 + l16] = f2bf(o[sub][dt][r] * inv);
      }
    }
  }
}

extern "C" void kernel_launch(void* const* d_in, const int* in_sizes, int n_in,
                              void* d_out, int out_size, void* d_ws, size_t ws_size,
                              hipStream_t stream) {
  const float* x = (const float*)d_in[0];
  const float* w_qkv = (const float*)d_in[1];
  const float* w_proj = (const float*)d_in[2];
  const float* b_proj = (const float*)d_in[3];
  float* outp = (float*)d_out;

  unsigned short* xb = (unsigned short*)d_ws;                     // 8192*768 bf16 (reused as attn out)
  unsigned short* wqkvT = xb + (size_t)ROWS * DIM;                // [2304][768]
  unsigned short* wprojT = wqkvT + (size_t)QKVN * DIM;            // [768][768]
  unsigned short* qkvb = wprojT + (size_t)DIM * DIM;              // [8192][2304]
  unsigned short* attnb = xb;                                     // alias: xb dead after qkv gemm

  prep_kernel<<<dim3(6144 + 1728 + 576), 256, 0, stream>>>(x, xb, w_qkv, wqkvT, w_proj, wprojT);
  // qkv: 64 row-tiles (8/XCD) x 12 col-tiles of 192 = 768 blocks = exactly 3/CU
  gemm192<true, true><<<dim3(768), 256, 0, stream>>>(xb, wqkvT, qkvb, nullptr, ROWS, QKVN, DIM, 8);
  attn_kernel<<<dim3(8 * 96), 512, 0, stream>>>(qkvb, attnb);
  // proj: 64 row-tiles (8/XCD) x 12 col-tiles of 64 = 768 blocks (3/CU)
  gemm64_proj<<<dim3(768), 256, 0, stream>>>(attnb, wprojT, outp, b_proj, ROWS, DIM, DIM, 8);
}

// Round 15
// 174.970 us; speedup vs baseline: 1.2018x; 1.0231x over previous
//
#include <hip/hip_runtime.h>
#include <hip/hip_bf16.h>

#define NH 12
#define HD 64
#define SEQ 1024
#define BATCH 8
#define DIM 768
#define QKVN 2304
#define ROWS 8192   // BATCH*SEQ

typedef __bf16 bf16x8 __attribute__((ext_vector_type(8)));
typedef float f32x4 __attribute__((ext_vector_type(4)));
typedef unsigned short u16x8 __attribute__((ext_vector_type(8)));
typedef unsigned short u16x4 __attribute__((ext_vector_type(4)));
typedef short s16x4 __attribute__((ext_vector_type(4)));

__device__ __forceinline__ unsigned short f2bf(float f) {
  union { float f; unsigned int u; } c; c.f = f;
  unsigned int u = c.u;
  u += 0x7fffu + ((u >> 16) & 1u);   // RNE; inputs are normal floats
  return (unsigned short)(u >> 16);
}

__device__ __forceinline__ unsigned int pk_bf16(float a, float b) {
  // packed RNE f32->bf16 pair (v_cvt_pk_bf16_f32 on gfx950)
  union { __hip_bfloat162 h; unsigned int w; } u;
  u.h = __float22bfloat162_rn(float2{a, b});
  return u.w;
}

__device__ __forceinline__ float exp2_fast(float x) {
  // raw v_exp_f32 (computes 2^x). q-scale has log2e folded in at the qkv GEMM,
  // so softmax base-2 here is mathematically exact vs base-e.
  float r;
  asm("v_exp_f32 %0, %1" : "=v"(r) : "v"(x));
  return r;
}

__device__ __forceinline__ void gload_lds16(const unsigned short* g, unsigned short* l) {
  __builtin_amdgcn_global_load_lds(
      (const __attribute__((address_space(1))) void*)g,
      (__attribute__((address_space(3))) void*)l, 16, 0, 0);
}

// ---------------- fused prep: f32->bf16 cast + both weight transposes ----------------
__device__ __forceinline__ void tr_tile(const float* __restrict__ src, unsigned short* __restrict__ dst,
                                        int R, int C, int bx, int by, float tile[32][33]) {
  int tx = threadIdx.x & 31, ty = threadIdx.x >> 5;   // 32 x 8
  int c0 = bx * 32, r0 = by * 32;
#pragma unroll
  for (int i = 0; i < 4; ++i)
    tile[ty + i * 8][tx] = src[(size_t)(r0 + ty + i * 8) * C + c0 + tx];
  __syncthreads();
#pragma unroll
  for (int i = 0; i < 4; ++i)
    dst[(size_t)(c0 + ty + i * 8) * R + r0 + tx] = f2bf(tile[tx][ty + i * 8]);
}

__global__ void prep_kernel(const float* __restrict__ x, unsigned short* __restrict__ xb,
                            const float* __restrict__ w_qkv, unsigned short* __restrict__ wqkvT,
                            const float* __restrict__ w_proj, unsigned short* __restrict__ wprojT) {
  __shared__ float tile[32][33];
  int blk = blockIdx.x;
  if (blk < 6144) {
    int i = blk * 256 + threadIdx.x;   // n4 = 8192*768/4 = 1572864 = 6144*256 exactly
    float4 v = ((const float4*)x)[i];
    unsigned int lo = pk_bf16(v.x, v.y), hi = pk_bf16(v.z, v.w);
    union { unsigned int w[2]; u16x4 o; } u; u.w[0] = lo; u.w[1] = hi;
    ((u16x4*)xb)[i] = u.o;
  } else if (blk < 6144 + 1728) {
    int t = blk - 6144;                // w_qkv: 768x2304 -> 24 x 72 tiles
    tr_tile(w_qkv, wqkvT, DIM, QKVN, t % 72, t / 72, tile);
  } else {
    int t = blk - 6144 - 1728;         // w_proj: 768x768 -> 24 x 24 tiles
    tr_tile(w_proj, wprojT, DIM, DIM, t % 24, t / 24, tile);
  }
}

// ---------------- 128x192 bf16 GEMM (qkv), dbuf, 1 barrier/K-iter ----------------
// R1 retile: 768 blocks = exactly 3/CU. R7 lesson: the implicit wave overlap at 3
// blocks/CU IS the pipeline — counted-vmcnt/triple-buffer grafts regressed.
template <bool BF16_OUT, bool SCALE_Q>
__global__ __launch_bounds__(256, 3) void gemm192(
    const unsigned short* __restrict__ A, const unsigned short* __restrict__ BT,
    void* __restrict__ Cout, const float* __restrict__ bias,
    int M, int N, int K, int nbyXCD) {
  __shared__ unsigned short As[2][128 * 32];   // 8 KB / buf
  __shared__ unsigned short Bs[2][192 * 32];   // 12 KB / buf
  const int tid = threadIdx.x;
  const int wave = tid >> 6, lane = tid & 63, quad = lane >> 4, l16 = lane & 15;
  const int wm = wave >> 1, wn = wave & 1;     // 2x2 waves -> per-wave 64x96
  const int g = blockIdx.x & 7, bi = blockIdx.x >> 3;
  const int by = g * nbyXCD + (bi % nbyXCD);
  const int bx = bi / nbyXCD;
  const int bm = by * 128, bn = bx * 192;

  const int r0 = tid >> 2, kc0 = (tid & 3) * 8;
  const unsigned short* Ag = A + (size_t)(bm + r0) * K + kc0;
  const unsigned short* Bg = BT + (size_t)(bn + r0) * K + kc0;
  unsigned short* AsB = &As[0][0];
  unsigned short* BsB = &Bs[0][0];
  const int wdst = (tid & ~63) * 8;   // wave-uniform LDS chunk base (u16)

#define STAGE_G(kt, b) do {                                                   \
    int koff_ = (kt) * 32;                                                    \
    gload_lds16(Ag + koff_,                    AsB + (b) * 4096 + wdst);      \
    gload_lds16(Ag + koff_ + (size_t)64 * K,   AsB + (b) * 4096 + wdst + 2048);\
    gload_lds16(Bg + koff_,                    BsB + (b) * 6144 + wdst);      \
    gload_lds16(Bg + koff_ + (size_t)64 * K,   BsB + (b) * 6144 + wdst + 2048);\
    gload_lds16(Bg + koff_ + (size_t)128 * K,  BsB + (b) * 6144 + wdst + 4096);\
  } while (0)

  f32x4 zero4 = {0.f, 0.f, 0.f, 0.f};
  f32x4 acc[4][6];
#pragma unroll
  for (int i = 0; i < 4; ++i)
#pragma unroll
    for (int j = 0; j < 6; ++j) acc[i][j] = zero4;

  const int nkt = K >> 5;
  STAGE_G(0, 0);   // prologue: tile 0 -> buf 0
  for (int kt = 0; kt < nkt; ++kt) {
    __syncthreads();   // buf[kt&1] staged; reads of buf[(kt+1)&1] from kt-1 done
    if (kt + 1 < nkt) STAGE_G(kt + 1, (kt + 1) & 1);
    const unsigned short* Ab = AsB + (kt & 1) * 4096;
    const unsigned short* Bb = BsB + (kt & 1) * 6144;
    bf16x8 af[4], bf[6];
#pragma unroll
    for (int mt = 0; mt < 4; ++mt)
      af[mt] = *(const bf16x8*)&Ab[(wm * 64 + mt * 16 + l16) * 32 + quad * 8];
#pragma unroll
    for (int nt = 0; nt < 6; ++nt)
      bf[nt] = *(const bf16x8*)&Bb[(wn * 96 + nt * 16 + l16) * 32 + quad * 8];
#pragma unroll
    for (int mt = 0; mt < 4; ++mt)
#pragma unroll
      for (int nt = 0; nt < 6; ++nt)
        acc[mt][nt] = __builtin_amdgcn_mfma_f32_16x16x32_bf16(af[mt], bf[nt], acc[mt][nt], 0, 0, 0);
  }
#undef STAGE_G

#pragma unroll
  for (int mt = 0; mt < 4; ++mt)
#pragma unroll
    for (int nt = 0; nt < 6; ++nt) {
      int col = bn + wn * 96 + nt * 16 + l16;
      float bv = BF16_OUT ? 0.f : bias[col];
      // q-scale 0.125 with log2e folded in (attn uses base-2 exp; exact fold)
      float scl = (SCALE_Q && col < DIM) ? 0.18033688011112042f : 1.0f;
#pragma unroll
      for (int r = 0; r < 4; ++r) {
        int row = bm + wm * 64 + mt * 16 + quad * 4 + r;
        float v = acc[mt][nt][r];
        if (BF16_OUT)
          ((unsigned short*)Cout)[(size_t)row * N + col] = f2bf(v * scl);
        else
          ((float*)Cout)[(size_t)row * N + col] = v + bv;
      }
    }
}

// ---------------- 128x64 bf16 GEMM for proj, BK=64 (R6-verified config) ----------------
// Chunk-XOR swizzle both sides. LDS 48 KB -> 3 blocks/CU. (256,4) caps VGPR at 128.
__global__ __launch_bounds__(256, 4) void gemm64_proj(
    const unsigned short* __restrict__ A, const unsigned short* __restrict__ BT,
    float* __restrict__ Cout, const float* __restrict__ bias,
    int M, int N, int K, int nbyXCD) {
  __shared__ unsigned short As[2][128 * 64];   // 16 KB / buf
  __shared__ unsigned short Bs[2][64 * 64];    // 8 KB / buf
  const int tid = threadIdx.x;
  const int wave = tid >> 6, lane = tid & 63, quad = lane >> 4, l16 = lane & 15;
  const int g = blockIdx.x & 7, bi = blockIdx.x >> 3;
  const int by = g * nbyXCD + (bi % nbyXCD);
  const int bx = bi / nbyXCD;
  const int bm = by * 128, bn = bx * 64;

  const int r0 = tid >> 3;                       // 0..31 (row within a 32-row call)
  const int csw = ((tid & 7) ^ (r0 & 7)) * 8;    // XOR-swizzled source col chunk
  const unsigned short* Ag = A + (size_t)(bm + r0) * K + csw;
  const unsigned short* Bg = BT + (size_t)(bn + r0) * K + csw;
  unsigned short* AsB = &As[0][0];
  unsigned short* BsB = &Bs[0][0];
  const int wdst = (tid & ~63) * 8;   // wave-uniform; per-lane dest = tid*8 (linear)

#define STAGE_P(kt, b) do {                                                     \
    int koff_ = (kt) * 64;                                                      \
    gload_lds16(Ag + koff_,                   AsB + (b) * 8192 + wdst);         \
    gload_lds16(Ag + koff_ + (size_t)32 * K,  AsB + (b) * 8192 + wdst + 2048);  \
    gload_lds16(Ag + koff_ + (size_t)64 * K,  AsB + (b) * 8192 + wdst + 4096);  \
    gload_lds16(Ag + koff_ + (size_t)96 * K,  AsB + (b) * 8192 + wdst + 6144);  \
    gload_lds16(Bg + koff_,                   BsB + (b) * 4096 + wdst);         \
    gload_lds16(Bg + koff_ + (size_t)32 * K,  BsB + (b) * 4096 + wdst + 2048);  \
  } while (0)

  f32x4 zero4 = {0.f, 0.f, 0.f, 0.f};
  f32x4 acc[2][4];
#pragma unroll
  for (int i = 0; i < 2; ++i)
#pragma unroll
    for (int j = 0; j < 4; ++j) acc[i][j] = zero4;

  const int nkt = K >> 6;   // 12
  STAGE_P(0, 0);
  for (int kt = 0; kt < nkt; ++kt) {
    __syncthreads();
    if (kt + 1 < nkt) STAGE_P(kt + 1, (kt + 1) & 1);
    const unsigned short* Ab = AsB + (kt & 1) * 8192;
    const unsigned short* Bb = BsB + (kt & 1) * 4096;
#pragma unroll
    for (int kk = 0; kk < 2; ++kk) {
      const int pc = ((kk * 4 + quad) ^ (l16 & 7)) * 8;   // physical chunk (swizzled)
      bf16x8 af[2], bf[4];
#pragma unroll
      for (int mt = 0; mt < 2; ++mt)
        af[mt] = *(const bf16x8*)&Ab[(wave * 32 + mt * 16 + l16) * 64 + pc];
#pragma unroll
      for (int nt = 0; nt < 4; ++nt)
        bf[nt] = *(const bf16x8*)&Bb[(nt * 16 + l16) * 64 + pc];
#pragma unroll
      for (int mt = 0; mt < 2; ++mt)
#pragma unroll
        for (int nt = 0; nt < 4; ++nt)
          acc[mt][nt] = __builtin_amdgcn_mfma_f32_16x16x32_bf16(af[mt], bf[nt], acc[mt][nt], 0, 0, 0);
    }
  }
#undef STAGE_P

#pragma unroll
  for (int mt = 0; mt < 2; ++mt)
#pragma unroll
    for (int nt = 0; nt < 4; ++nt) {
      int col = bn + nt * 16 + l16;
      float bv = bias[col];
#pragma unroll
      for (int r = 0; r < 4; ++r) {
        int row = bm + wave * 32 + mt * 16 + quad * 4 + r;
        Cout[(size_t)row * N + col] = acc[mt][nt][r] + bv;
      }
    }
}

// ---------------- flash attention: Q-tile 128 (8 waves), KV-tile 64 ----------------
// R14: FINAL — R6-exact config (45.0-45.7 us, 4 verified runs). Perturbation space
// fully mapped, all directions regressed: R2 fat-waves@12w (55.5), R4 KVBLK128@1blk
// (59.5), R8 reorder (51.4), R11 key-split@24w spills (84.0), R13 key-split@16w
// clean (51.2). R13 falsified the LDS-throughput model: half LDS traffic at 16
// waves LOST to full traffic at 24 waves — the kernel is TLP/latency-bound and
// 24-wave residency dominates. This config is the structure's verified optimum.
#define VS 76   // Vts row stride (u16)
__global__ __launch_bounds__(512, 6) void attn_kernel(
    const unsigned short* __restrict__ qkv, unsigned short* __restrict__ out) {
  __shared__ unsigned short Ks[2][64 * 64];     // [kk][n][32] split layout per buffer, 8 KB each
  __shared__ unsigned short Vts[2][64 * VS];    // V^T [d][n], 9.5 KB each

  const int tid = threadIdx.x;
  const int wave = tid >> 6, lane = tid & 63, quad = lane >> 4, l16 = lane & 15;
  // XCD-locality swizzle: all 8 q-tiles of one (b,h) share id%8 -> same XCD
  const int x = blockIdx.x;
  const int qt = (x >> 3) & 7;
  const int bh = (x & 7) + 8 * (x >> 6);
  const int b = bh / NH, h = bh % NH;
  const int qcol = h * HD, kcol = DIM + h * HD, vcol = 2 * DIM + h * HD;
  const int rowQ0 = b * SEQ + qt * 128;
  const int rowKV0 = b * SEQ;

  // staging index precompute
  const int kk_s = tid >> 8, rem_s = tid & 255, n_s = rem_s >> 2, kc_s = rem_s & 3;
  const unsigned short* kgp = qkv + (size_t)(rowKV0 + n_s) * QKVN + kcol + kk_s * 32 + kc_s * 8;
  unsigned short* klp = &Ks[0][0] + (tid & ~63) * 8;   // wave-uniform base (u16 units)
  const int vn = tid & 63, vd0 = (tid >> 6) * 8;
  const unsigned short* vgp = qkv + (size_t)(rowKV0 + vn) * QKVN + vcol + vd0;

  // ---- Q fragments straight from global ----
  bf16x8 qf[2];
  {
    const unsigned short* qp = qkv + (size_t)(rowQ0 + wave * 16 + l16) * QKVN + qcol + quad * 8;
    qf[0] = *(const bf16x8*)qp;
    qf[1] = *(const bf16x8*)(qp + 32);
  }

  // ---- prologue: stage tile 0 into buffer 0 ----
  gload_lds16(kgp, klp);
  {
    u16x8 v0 = *(const u16x8*)vgp;
    unsigned short* vb = &Vts[0][0];
#pragma unroll
    for (int e = 0; e < 8; ++e)
      vb[(vd0 + e) * VS + vn] = v0[e];
  }

  f32x4 zero4 = {0.f, 0.f, 0.f, 0.f};
  f32x4 o[4];
#pragma unroll
  for (int dt = 0; dt < 4; ++dt) o[dt] = zero4;
  float lsum = 0.f;

  for (int jt = 0; jt < 16; ++jt) {
    __syncthreads();   // drains K-DMA(jt) + vload(jt): both one compute phase old
    u16x8 vnext;
    if (jt < 15) {
      gload_lds16(kgp + (size_t)(jt + 1) * 64 * QKVN, klp + ((jt + 1) & 1) * 4096);
      vnext = *(const u16x8*)(vgp + (size_t)(jt + 1) * 64 * QKVN);
    }

    const unsigned short* Kb = &Ks[jt & 1][0];
    const unsigned short* Vb = &Vts[jt & 1][0];

    // ---- S^T = K Q^T : rows=keys, cols=queries ----
    f32x4 s[4];
#pragma unroll
    for (int nt = 0; nt < 4; ++nt) s[nt] = zero4;
    __builtin_amdgcn_s_setprio(1);
#pragma unroll
    for (int kk = 0; kk < 2; ++kk)
#pragma unroll
      for (int nt = 0; nt < 4; ++nt) {
        bf16x8 kf = *(const bf16x8*)&Kb[kk * 2048 + (nt * 16 + l16) * 32 + quad * 8];
        s[nt] = __builtin_amdgcn_mfma_f32_16x16x32_bf16(kf, qf[kk], s[nt], 0, 0, 0);
      }
    __builtin_amdgcn_s_setprio(0);

    // ---- p = 2^s (log2e pre-folded); packed cvt to bf16 A-frags; l partials ----
    s16x4 pf[4];
#pragma unroll
    for (int nt = 0; nt < 4; ++nt) {
      float p0 = exp2_fast(s[nt][0]);
      float p1 = exp2_fast(s[nt][1]);
      float p2 = exp2_fast(s[nt][2]);
      float p3 = exp2_fast(s[nt][3]);
      lsum += (p0 + p1) + (p2 + p3);
      union { unsigned int w[2]; s16x4 v; } u;
      u.w[0] = pk_bf16(p0, p1);
      u.w[1] = pk_bf16(p2, p3);
      pf[nt] = u.v;
    }

    // ---- O += P V  (P^T regs as A-frag, V^T LDS as B-frag, K=16 chunks) ----
    __builtin_amdgcn_s_setprio(1);
#pragma unroll
    for (int nt = 0; nt < 4; ++nt)
#pragma unroll
      for (int dt = 0; dt < 4; ++dt) {
        s16x4 vv = *(const s16x4*)&Vb[(dt * 16 + l16) * VS + nt * 16 + quad * 4];
        o[dt] = __builtin_amdgcn_mfma_f32_16x16x16bf16_1k(pf[nt], vv, o[dt], 0, 0, 0);
      }
    __builtin_amdgcn_s_setprio(0);

    // ---- sink next V's LDS writes after compute (vnext is compute-phase old) ----
    if (jt < 15) {
      unsigned short* vb = &Vts[(jt + 1) & 1][0];
#pragma unroll
      for (int e = 0; e < 8; ++e)
        vb[(vd0 + e) * VS + vn] = vnext[e];
    }
  }

  // ---- epilogue: reduce l across quads, redistribute, normalize, store ----
  float l = lsum;
  l += __shfl_xor(l, 16);
  l += __shfl_xor(l, 32);   // full sum for query l16
#pragma unroll
  for (int r = 0; r < 4; ++r) {
    float inv = 1.f / __shfl(l, quad * 4 + r);
    int row = rowQ0 + wave * 16 + quad * 4 + r;
#pragma unroll
    for (int dt = 0; dt < 4; ++dt)
      out[(size_t)row * DIM + h * HD + dt * 16 + l16] = f2bf(o[dt][r] * inv);
  }
}

extern "C" void kernel_launch(void* const* d_in, const int* in_sizes, int n_in,
                              void* d_out, int out_size, void* d_ws, size_t ws_size,
                              hipStream_t stream) {
  const float* x = (const float*)d_in[0];
  const float* w_qkv = (const float*)d_in[1];
  const float* w_proj = (const float*)d_in[2];
  const float* b_proj = (const float*)d_in[3];
  float* outp = (float*)d_out;

  unsigned short* xb = (unsigned short*)d_ws;                     // 8192*768 bf16 (reused as attn out)
  unsigned short* wqkvT = xb + (size_t)ROWS * DIM;                // [2304][768]
  unsigned short* wprojT = wqkvT + (size_t)QKVN * DIM;            // [768][768]
  unsigned short* qkvb = wprojT + (size_t)DIM * DIM;              // [8192][2304]
  unsigned short* attnb = xb;                                     // alias: xb dead after qkv gemm

  prep_kernel<<<dim3(6144 + 1728 + 576), 256, 0, stream>>>(x, xb, w_qkv, wqkvT, w_proj, wprojT);
  // qkv: 64 row-tiles (8/XCD) x 12 col-tiles of 192 = 768 blocks = exactly 3/CU
  gemm192<true, true><<<dim3(768), 256, 0, stream>>>(xb, wqkvT, qkvb, nullptr, ROWS, QKVN, DIM, 8);
  attn_kernel<<<dim3(8 * 96), 512, 0, stream>>>(qkvb, attnb);
  // proj: 64 row-tiles (8/XCD) x 12 col-tiles of 64 = 768 blocks (3/CU)
  gemm64_proj<<<dim3(768), 256, 0, stream>>>(attnb, wprojT, outp, b_proj, ROWS, DIM, DIM, 8);
}